// Round 12
// baseline (145.360 us; speedup 1.0000x reference)
//
#include <hip/hip_runtime.h>
#include <hip/hip_bf16.h>
#include <cstdint>

typedef __bf16 bf16;
typedef __bf16 bf16x4 __attribute__((ext_vector_type(4)));
typedef __bf16 bf16x8 __attribute__((ext_vector_type(8)));
typedef float f32x4 __attribute__((ext_vector_type(4)));

#define B_ 16
#define N_ 1024
#define FEAT_ 768
#define H_ 8
#define NONGT_ 20
#define M_ 10
#define POS_ 64
#define DG_ 96
#define KTOT_ 30
#define KPAD_ 32
#define ROWS_ (B_*N_)
#define SCALE_M 9.797958971132712f
#define INV_SQRT_DG 0.10206207261596575f
#define NEG_ -9.0e15f

__device__ __forceinline__ bf16x8 cvt8(float4 a, float4 b) {
  bf16x8 o;
  o[0]=(bf16)a.x; o[1]=(bf16)a.y; o[2]=(bf16)a.z; o[3]=(bf16)a.w;
  o[4]=(bf16)b.x; o[5]=(bf16)b.y; o[6]=(bf16)b.z; o[7]=(bf16)b.w;
  return o;
}

// ---------------- prep: Wk_t + Wout hi/lo + V + mk-keys + Abf (plain bf16) --------
__global__ void prep_kernel(const float* __restrict__ Wk,
                            const float* __restrict__ Wout, const float* __restrict__ roi,
                            const float* __restrict__ aux, const float* __restrict__ m_v,
                            const float* __restrict__ m_k,
                            bf16* __restrict__ Wk_t,
                            bf16* __restrict__ Whi, bf16* __restrict__ Wlo,
                            bf16* __restrict__ Vbf, bf16* __restrict__ kbuf,
                            bf16* __restrict__ Abf)
{
  int idx = blockIdx.x * blockDim.x + threadIdx.x;
  int stride = gridDim.x * blockDim.x;
  for (int i = idx; i < FEAT_*FEAT_; i += stride) {
    int k = i / FEAT_, n = i % FEAT_;            // i walks Wk row-major: Wk[k][n]
    Wk_t[(size_t)n*FEAT_ + k] = (bf16)Wk[i];
    float w = Wout[i];                           // Wout rows already [(h*DG+g)][f]
    bf16 hi = (bf16)w;
    Whi[i] = hi;
    Wlo[i] = (bf16)(w - (float)hi);
  }
  for (int i = idx; i < B_*KPAD_*FEAT_; i += stride) {
    int f = i % FEAT_;
    int r = (i / FEAT_) % KPAD_;
    int b = i / (FEAT_*KPAD_);
    float v;
    if (r < NONGT_)      v = roi[((size_t)b*N_ + r)*FEAT_ + f];
    else if (r < KTOT_)  v = SCALE_M * m_v[(r-NONGT_)*FEAT_ + f] * aux[b*FEAT_ + f];
    else                 v = 0.f;
    Vbf[i] = (bf16)v;
  }
  // kbuf rows 20..31 (mk keys + zero pad rows 30,31); rows 0..19 from small_kernel
  for (int i = idx; i < B_*12*FEAT_; i += stride) {
    int f = i % FEAT_;
    int rr = (i / FEAT_) % 12;
    int b = i / (FEAT_*12);
    float v = (rr < M_) ? SCALE_M * m_k[rr*FEAT_ + f] * aux[b*FEAT_ + f] : 0.f;
    kbuf[((size_t)b*KPAD_ + NONGT_ + rr)*FEAT_ + f] = (bf16)v;
  }
  // roi -> Abf bf16, plain layout (read per-lane by attn QK)
  const int total8 = ROWS_*FEAT_/8;
  for (int i = idx; i < total8; i += stride) {
    const float4* p = (const float4*)(roi + (size_t)i*8);
    *(bf16x8*)(Abf + (size_t)i*8) = cvt8(p[0], p[1]);
  }
}

// ---------------- posbias v3: one thread per (row,j), f64 accum, posb [row][j][h] ---
__global__ __launch_bounds__(256, 8) void posbias_kernel(
    const float* __restrict__ pe, const float* __restrict__ Wpos,
    const float* __restrict__ bpos, float* __restrict__ posb)
{
  __shared__ __align__(16) float sW[POS_*H_];
  __shared__ float sbp[H_];
  const int tid = threadIdx.x;
  sW[tid] = Wpos[tid];
  sW[256 + tid] = Wpos[256 + tid];
  if (tid < H_) sbp[tid] = bpos[tid];
  __syncthreads();
  const size_t g = (size_t)blockIdx.x*256 + tid;
  const float4* per = (const float4*)(pe + g*POS_);
  double acc[8];
  #pragma unroll
  for (int h = 0; h < 8; ++h) acc[h] = (double)sbp[h];
  #pragma unroll
  for (int p4 = 0; p4 < 16; ++p4) {
    float4 a = per[p4];
    float av[4] = {a.x, a.y, a.z, a.w};
    #pragma unroll
    for (int e = 0; e < 4; ++e) {
      const double ad = (double)av[e];
      const float* wp = sW + (p4*4 + e)*8;
      #pragma unroll
      for (int h = 0; h < 8; ++h)
        acc[h] = fma(ad, (double)wp[h], acc[h]);
    }
  }
  float o[8];
  #pragma unroll
  for (int h = 0; h < 8; ++h) {
    float x = (float)acc[h];
    o[h] = __logf(fmaxf(fmaxf(x, 0.f), 1e-6f));
  }
  float4* po = (float4*)(posb + g*8);
  po[0] = (float4){o[0], o[1], o[2], o[3]};
  po[1] = (float4){o[4], o[5], o[6], o[7]};
}

// ---------------- small GEMMs: one wave per 16x16 tile (K-GEMM + VW-GEMM) ----------
__global__ __launch_bounds__(256, 4) void small_kernel(
    const float* __restrict__ roi, const bf16* __restrict__ Wk_t,
    const bf16* __restrict__ Vbf, const bf16* __restrict__ Whi, const bf16* __restrict__ Wlo,
    const float* __restrict__ bk, bf16* __restrict__ kbuf,
    bf16* __restrict__ vwT_hi, bf16* __restrict__ vwT_lo)
{
  const int tid = threadIdx.x;
  const int w = tid >> 6, l = tid & 63;
  const int fr = l & 15, fq = l >> 4, fko = fq << 3;
  const int widx = blockIdx.x*4 + w;          // [0, 3072)
  const int cbase = (widx % 48) * 16;
  const int by = widx / 48;                   // [0,64)
  f32x4 acc = {};
  if (by < 32) {
    const float* Ap = roi + ((size_t)(by >> 1)*N_ + (by & 1)*16 + fr)*FEAT_ + fko;
    const bf16* Bp = Wk_t + (size_t)(cbase + fr)*FEAT_ + fko;
    #pragma unroll
    for (int kt = 0; kt < FEAT_/32; ++kt) {
      float4 a0 = *(const float4*)(Ap + kt*32);
      float4 a1 = *(const float4*)(Ap + kt*32 + 4);
      bf16x8 b = *(const bf16x8*)(Bp + kt*32);
      acc = __builtin_amdgcn_mfma_f32_16x16x32_bf16(cvt8(a0, a1), b, acc, 0, 0, 0);
    }
    const float bv = bk[cbase + fr];
    #pragma unroll
    for (int r = 0; r < 4; ++r) {
      const int rl = (by & 1)*16 + fq*4 + r;
      if (rl < NONGT_)
        kbuf[((size_t)(by >> 1)*KPAD_ + rl)*FEAT_ + cbase + fr] = (bf16)(acc[r] + bv);
    }
  } else {
    const int rt = by - 32;
    const bf16* Ap = Vbf + ((size_t)rt*16 + fr)*FEAT_ + fko;
    const bf16* B1 = Whi + (size_t)(cbase + fr)*FEAT_ + fko;
    const bf16* B2 = Wlo + (size_t)(cbase + fr)*FEAT_ + fko;
    f32x4 acc2 = {};
    #pragma unroll
    for (int kt = 0; kt < FEAT_/32; ++kt) {
      bf16x8 a = *(const bf16x8*)(Ap + kt*32);
      acc  = __builtin_amdgcn_mfma_f32_16x16x32_bf16(a, *(const bf16x8*)(B1 + kt*32), acc,  0, 0, 0);
      acc2 = __builtin_amdgcn_mfma_f32_16x16x32_bf16(a, *(const bf16x8*)(B2 + kt*32), acc2, 0, 0, 0);
    }
    #pragma unroll
    for (int r = 0; r < 4; ++r) {
      const int grow = rt*16 + fq*4 + r;
      const int b = grow >> 5, key = grow & 31;
      float vv = acc[r] + acc2[r];
      bf16 vh = (bf16)vv;
      size_t addr = ((size_t)b*FEAT_ + cbase + fr)*KPAD_ + key;
      vwT_hi[addr] = vh;
      vwT_lo[addr] = (bf16)(vv - (float)vh);
    }
  }
}

// ---------------- kq: kq[b][h*32+j][f] = sum_d Wq[f][h*96+d] * k[b][j][h*96+d] -----
// + qkb[b][h*32+j] = sum_d bq[h*96+d] * k[b][j][h*96+d]   (bq folding)
// MFMA: C[j][f] = mfma(ks_frag(j rows), wq_frag(f rows)); K=96 (3 kt).
__global__ __launch_bounds__(256, 4) void kq_kernel(
    const float* __restrict__ Wq, const float* __restrict__ bq,
    const bf16* __restrict__ kbuf,
    bf16* __restrict__ kq, float* __restrict__ qkb)
{
  const int b = blockIdx.x >> 3, h = blockIdx.x & 7;
  const int tid = threadIdx.x;
  const int w = tid >> 6, l = tid & 63;
  const int fr = l & 15, fq = l >> 4, fko = fq << 3;
  // hoist key fragments (shared across all f-tiles)
  bf16x8 ks0[3], ks1[3];
  const bf16* kb = kbuf + ((size_t)b*KPAD_)*FEAT_ + h*DG_ + fko;
  #pragma unroll
  for (int kt = 0; kt < 3; ++kt) {
    ks0[kt] = *(const bf16x8*)(kb + (size_t)fr*FEAT_ + kt*32);
    ks1[kt] = *(const bf16x8*)(kb + (size_t)(16 + fr)*FEAT_ + kt*32);
  }
  bf16* kqb = kq + ((size_t)b*256 + h*32)*FEAT_;
  #pragma unroll
  for (int ft = 0; ft < 12; ++ft) {
    const int f0 = (w*12 + ft) * 16;
    f32x4 acc0 = {}, acc1 = {};
    #pragma unroll
    for (int kt = 0; kt < 3; ++kt) {
      const float* wrow = Wq + (size_t)(f0 + fr)*FEAT_ + h*DG_ + kt*32 + fko;
      bf16x8 wq = cvt8(*(const float4*)wrow, *(const float4*)(wrow + 4));
      acc0 = __builtin_amdgcn_mfma_f32_16x16x32_bf16(ks0[kt], wq, acc0, 0, 0, 0);
      acc1 = __builtin_amdgcn_mfma_f32_16x16x32_bf16(ks1[kt], wq, acc1, 0, 0, 0);
    }
    #pragma unroll
    for (int r = 0; r < 4; ++r) {
      kqb[(size_t)(fq*4 + r)*FEAT_ + f0 + fr]      = (bf16)acc0[r];
      kqb[(size_t)(16 + fq*4 + r)*FEAT_ + f0 + fr] = (bf16)acc1[r];
    }
  }
  // qkb: wave 0, lanes 0..31 -> key j
  if (w == 0 && l < 32) {
    const bf16* kr = kbuf + ((size_t)b*KPAD_ + l)*FEAT_ + h*DG_;
    float s = 0.f;
    for (int d = 0; d < DG_; ++d) s = fmaf(bq[h*DG_ + d], (float)kr[d], s);
    qkb[b*256 + h*32 + l] = s;
  }
}

// ---------------- attn_v3: logits = Abf @ kq^T (K=768) + softmax + PV --------------
// grid 512 linear: x=bid&7 (XCD), jj=bid>>3; b = x*2+(jj>>5), nt = jj&31 -> 32 rows.
// Wave w owns heads 2w,2w+1 for both 16-row groups. kq[b] (393KB) stays L2-local.
__global__ __launch_bounds__(256, 2) void attn_kernel(
    const bf16* __restrict__ Abf, const bf16* __restrict__ kq,
    const float* __restrict__ qkb,
    const bf16* __restrict__ vwT_hi, const bf16* __restrict__ vwT_lo,
    const float* __restrict__ posb, const int* __restrict__ adj,
    const float* __restrict__ lb, const float* __restrict__ bout,
    float* __restrict__ out)
{
  __shared__ __align__(16) bf16 sph[H_*16*40];
  __shared__ __align__(16) bf16 spl[H_*16*40];
  const int tid = threadIdx.x;
  const int w = tid >> 6, l = tid & 63;
  const int fr = l & 15, fq = l >> 4, fko = fq << 3;
  const int x = blockIdx.x & 7, jj = blockIdx.x >> 3;
  const int b = x*2 + (jj >> 5);
  const int row0 = (jj & 31) * 32;
  const size_t rabs0 = (size_t)b*N_ + row0 + fr;

  // ---- QK: 8 accs (2 rowgroups x 2 heads x 2 key-tiles), K=768 ----
  const bf16* qp0 = Abf + rabs0*FEAT_ + fko;
  const bf16* qp1 = qp0 + (size_t)16*FEAT_;
  const bf16* kqb = kq + (size_t)b*256*FEAT_ + fko;
  const bf16* kp00 = kqb + (size_t)((2*w)*32 + fr)*FEAT_;
  const bf16* kp01 = kqb + (size_t)((2*w)*32 + 16 + fr)*FEAT_;
  const bf16* kp10 = kqb + (size_t)((2*w + 1)*32 + fr)*FEAT_;
  const bf16* kp11 = kqb + (size_t)((2*w + 1)*32 + 16 + fr)*FEAT_;
  f32x4 acc[2][2][2] = {};
  #pragma unroll 4
  for (int kt = 0; kt < 24; ++kt) {
    const int ko = kt*32;
    bf16x8 qa0 = *(const bf16x8*)(qp0 + ko);
    bf16x8 qa1 = *(const bf16x8*)(qp1 + ko);
    bf16x8 k00 = *(const bf16x8*)(kp00 + ko);
    bf16x8 k01 = *(const bf16x8*)(kp01 + ko);
    bf16x8 k10 = *(const bf16x8*)(kp10 + ko);
    bf16x8 k11 = *(const bf16x8*)(kp11 + ko);
    acc[0][0][0] = __builtin_amdgcn_mfma_f32_16x16x32_bf16(k00, qa0, acc[0][0][0], 0, 0, 0);
    acc[0][0][1] = __builtin_amdgcn_mfma_f32_16x16x32_bf16(k01, qa0, acc[0][0][1], 0, 0, 0);
    acc[0][1][0] = __builtin_amdgcn_mfma_f32_16x16x32_bf16(k10, qa0, acc[0][1][0], 0, 0, 0);
    acc[0][1][1] = __builtin_amdgcn_mfma_f32_16x16x32_bf16(k11, qa0, acc[0][1][1], 0, 0, 0);
    acc[1][0][0] = __builtin_amdgcn_mfma_f32_16x16x32_bf16(k00, qa1, acc[1][0][0], 0, 0, 0);
    acc[1][0][1] = __builtin_amdgcn_mfma_f32_16x16x32_bf16(k01, qa1, acc[1][0][1], 0, 0, 0);
    acc[1][1][0] = __builtin_amdgcn_mfma_f32_16x16x32_bf16(k10, qa1, acc[1][1][0], 0, 0, 0);
    acc[1][1][1] = __builtin_amdgcn_mfma_f32_16x16x32_bf16(k11, qa1, acc[1][1][1], 0, 0, 0);
  }

  // ---- epilogue per (rowgroup, head): bias/mask -> softmax -> P -> PV ----
  #pragma unroll
  for (int rg = 0; rg < 2; ++rg) {
    const size_t rabs = rabs0 + rg*16;
    const int*   adjr = adj + rabs*20;
    const float* lbr  = lb  + rabs*20;
    const float* pbr  = posb + rabs*160;          // layout [j][h]
    #pragma unroll
    for (int hi = 0; hi < 2; ++hi) {
      const int h = w*2 + hi;
      const float* qkbp = qkb + b*256 + h*32;
      float lg[2][4];
      #pragma unroll
      for (int r = 0; r < 4; ++r) {
        int j0 = fq*4 + r;
        float v0 = (acc[rg][hi][0][r] + qkbp[j0]) * INV_SQRT_DG;
        v0 = (adjr[j0] > 0 ? v0 + pbr[j0*8 + h] : NEG_) + lbr[j0];
        lg[0][r] = v0;
        int j1 = 16 + fq*4 + r;
        float v1 = (acc[rg][hi][1][r] + qkbp[j1]) * INV_SQRT_DG;
        if (j1 < NONGT_)      v1 = (adjr[j1] > 0 ? v1 + pbr[j1*8 + h] : NEG_) + lbr[j1];
        else if (j1 >= KTOT_) v1 = -3.0e38f;
        lg[1][r] = v1;
      }
      float m = lg[0][0];
      #pragma unroll
      for (int jt = 0; jt < 2; ++jt)
        #pragma unroll
        for (int r = 0; r < 4; ++r) m = fmaxf(m, lg[jt][r]);
      m = fmaxf(m, __shfl_xor(m, 16));
      m = fmaxf(m, __shfl_xor(m, 32));
      float s = 0.f;
      float e[2][4];
      #pragma unroll
      for (int jt = 0; jt < 2; ++jt)
        #pragma unroll
        for (int r = 0; r < 4; ++r) { e[jt][r] = __expf(lg[jt][r] - m); s += e[jt][r]; }
      s += __shfl_xor(s, 16);
      s += __shfl_xor(s, 32);
      const float inv = 1.f / s;
      #pragma unroll
      for (int jt = 0; jt < 2; ++jt) {
        bf16x4 ph, pl;
        #pragma unroll
        for (int r = 0; r < 4; ++r) {
          float p = e[jt][r] * inv;
          ph[r] = (bf16)p;
          pl[r] = (bf16)(p - (float)ph[r]);
        }
        const int off = (h*16 + fr)*40 + jt*16 + fq*4;
        *(bf16x4*)(sph + off) = ph;
        *(bf16x4*)(spl + off) = pl;
      }
      bf16x8 pa_h = *(const bf16x8*)(sph + (h*16 + fr)*40 + fko);
      bf16x8 pa_l = *(const bf16x8*)(spl + (h*16 + fr)*40 + fko);
      #pragma unroll
      for (int ct = 0; ct < 6; ++ct) {
        const int col = h*DG_ + ct*16 + fr;
        const size_t vaddr = ((size_t)b*FEAT_ + col)*KPAD_ + fko;
        bf16x8 vh = *(const bf16x8*)(vwT_hi + vaddr);
        bf16x8 vl = *(const bf16x8*)(vwT_lo + vaddr);
        f32x4 o = {};
        o = __builtin_amdgcn_mfma_f32_16x16x32_bf16(pa_h, vh, o, 0, 0, 0);
        o = __builtin_amdgcn_mfma_f32_16x16x32_bf16(pa_h, vl, o, 0, 0, 0);
        o = __builtin_amdgcn_mfma_f32_16x16x32_bf16(pa_l, vh, o, 0, 0, 0);
        const float bv = bout[col];
        #pragma unroll
        for (int r = 0; r < 4; ++r)
          out[(rabs - fr + fq*4 + r)*FEAT_ + col] = o[r] + bv;
      }
    }
  }
}

extern "C" void kernel_launch(void* const* d_in, const int* in_sizes, int n_in,
                              void* d_out, int out_size, void* d_ws, size_t ws_size,
                              hipStream_t stream) {
  const float* roi  = (const float*)d_in[0];
  const int*   adj  = (const int*)  d_in[1];
  const float* pe   = (const float*)d_in[2];
  const float* lb   = (const float*)d_in[3];
  const float* aux  = (const float*)d_in[4];
  const float* Wq   = (const float*)d_in[5];
  const float* bq   = (const float*)d_in[6];
  const float* Wk   = (const float*)d_in[7];
  const float* bk   = (const float*)d_in[8];
  const float* Wpos = (const float*)d_in[9];
  const float* bpos = (const float*)d_in[10];
  const float* m_k  = (const float*)d_in[11];
  const float* m_v  = (const float*)d_in[12];
  const float* Wout = (const float*)d_in[13];
  const float* bout = (const float*)d_in[14];
  float* out = (float*)d_out;

  char* pw = (char*)d_ws;
  auto carve = [&](size_t bytes) -> void* {
    void* r = pw; pw += (bytes + 255) & ~(size_t)255; return r;
  };
  bf16*  Abf    = (bf16*) carve((size_t)ROWS_*FEAT_*2);
  bf16*  Wk_t   = (bf16*) carve((size_t)FEAT_*FEAT_*2);
  bf16*  Whi    = (bf16*) carve((size_t)FEAT_*FEAT_*2);
  bf16*  Wlo    = (bf16*) carve((size_t)FEAT_*FEAT_*2);
  bf16*  Vbf    = (bf16*) carve((size_t)B_*KPAD_*FEAT_*2);
  bf16*  kbuf   = (bf16*) carve((size_t)B_*KPAD_*FEAT_*2);
  bf16*  vwT_hi = (bf16*) carve((size_t)B_*FEAT_*KPAD_*2);
  bf16*  vwT_lo = (bf16*) carve((size_t)B_*FEAT_*KPAD_*2);
  bf16*  kq     = (bf16*) carve((size_t)B_*256*FEAT_*2);
  float* qkb    = (float*)carve((size_t)B_*256*4);
  float* posb   = (float*)carve((size_t)ROWS_*160*4);

  posbias_kernel<<<dim3(ROWS_*NONGT_/256), dim3(256), 0, stream>>>(pe, Wpos, bpos, posb);
  prep_kernel<<<dim3(2048), dim3(256), 0, stream>>>(Wk, Wout, roi, aux, m_v, m_k,
                                                    Wk_t, Whi, Wlo, Vbf, kbuf, Abf);
  small_kernel<<<dim3(768), dim3(256), 0, stream>>>(roi, Wk_t, Vbf, Whi, Wlo,
                                                    bk, kbuf, vwT_hi, vwT_lo);
  kq_kernel<<<dim3(128), dim3(256), 0, stream>>>(Wq, bq, kbuf, kq, qkb);
  attn_kernel<<<dim3(512), dim3(256), 0, stream>>>(Abf, kq, qkb, vwT_hi, vwT_lo,
                                                   posb, adj, lb, bout, out);
}